// Round 9
// baseline (217.195 us; speedup 1.0000x reference)
//
#include <hip/hip_runtime.h>
#include <stdint.h>
#include <stddef.h>

// ---------------------------------------------------------------------------
// AttentionLayer: x[4,2048,1024] f32, W_qkv[3072,1024], b_qkv[3072],
//                 W_proj[1024,1024], b_proj[1024]  -> out[4,2048,1024] f32
// Uniform GEMM "gp": 128x128 tile, BK=32, 4 waves, 32KB LDS dbuf ->
// 4 blocks/CU, compiler-scheduled loop (NO asm walls: fine-grained lgkmcnt
// interleaves ds_read with MFMA; __syncthreads once per K-tile). 8x8 L2
// block-tiling + read swizzle retained. exp-softmax folded into QK^T;
// rowsum_inv + PV row-scale complete it.
// ---------------------------------------------------------------------------

typedef __attribute__((ext_vector_type(8))) short bf16x8;
typedef __attribute__((ext_vector_type(4))) float f32x4;

__device__ __forceinline__ unsigned short f2bf(float f) {
  unsigned u = __float_as_uint(f);
  u += 0x7fffu + ((u >> 16) & 1u);
  return (unsigned short)(u >> 16);
}
__device__ __forceinline__ float bf2f(unsigned short h) {
  return __uint_as_float(((unsigned)h) << 16);
}

typedef const __attribute__((address_space(1))) void* gas_ptr;
typedef __attribute__((address_space(3))) void* las_ptr;

__device__ __forceinline__ void gload_lds16(const void* g, void* l) {
  __builtin_amdgcn_global_load_lds((gas_ptr)(uintptr_t)g,
                                   (las_ptr)(uint32_t)(uintptr_t)l, 16, 0, 0);
}

__device__ __forceinline__ f32x4 mfma16(bf16x8 a, bf16x8 b, f32x4 c) {
  return __builtin_amdgcn_mfma_f32_16x16x32_bf16(a, b, c, 0, 0, 0);
}

// --------------------------- fp32 -> bf16 cast -----------------------------
__global__ __launch_bounds__(256) void cvt_f32_bf16(
    const float* __restrict__ in, unsigned short* __restrict__ out, int n) {
  int i = (blockIdx.x * blockDim.x + threadIdx.x) * 4;
  int stride = gridDim.x * blockDim.x * 4;
  for (; i < n; i += stride) {
    float4 v = *reinterpret_cast<const float4*>(in + i);
    ushort4 o;
    o.x = f2bf(v.x); o.y = f2bf(v.y); o.z = f2bf(v.z); o.w = f2bf(v.w);
    *reinterpret_cast<ushort4*>(out + i) = o;
  }
}

// ================================ gp =======================================
// LDS tile [128 rows][32 k] bf16 per operand (8KB). 16B-group swizzle:
// stored group = logical ^ ((row>>1)&3)  (2-way residual conflict = free).
// Global source pre-swizzled (rule 21); LDS dest linear for global_load_lds.

__device__ __forceinline__ void stage32(const unsigned short* __restrict__ P,
                                        int ld, unsigned short* dst, int tid) {
  const int w = tid >> 6, l = tid & 63;
  const int rr = l >> 2;
  const int cswz = (((l & 3) ^ ((l >> 3) & 3)) * 8);
#pragma unroll
  for (int c = 0; c < 2; ++c) {
    int r = c * 64 + w * 16 + rr;
    gload_lds16(P + (size_t)r * ld + cswz, dst + c * 2048 + w * 512);
  }
}

template <bool OUT_BF16, bool HAS_BIAS, bool EXPOUT, bool RSCALE>
__global__ __launch_bounds__(256, 4) void gp(
    const unsigned short* __restrict__ A, const unsigned short* __restrict__ B,
    void* __restrict__ Cv, const float* __restrict__ bias,
    const float* __restrict__ rowsc, int rsStride,
    int K, int lda, int ldb, int ldc,
    long long strideA, long long strideB, long long strideC, float alpha) {
  __shared__ unsigned short lds[2][2][128 * 32];  // [buf][A|B] 32KB total

  const int bz = blockIdx.z;
  const int gx = gridDim.x;
  int lin = blockIdx.y * gx + blockIdx.x;
  int bx, by;
  {
    const int nwg = gx * gridDim.y;
    const int q = nwg >> 3;                 // XCD chunking (nwg % 8 == 0)
    lin = (lin & 7) * q + (lin >> 3);
    const int t = lin >> 6, r = lin & 63;   // 8x8 tile ordering per 64 blocks
    const int tilesX = gx >> 3;
    bx = (t % tilesX) * 8 + (r & 7);
    by = (t / tilesX) * 8 + (r >> 3);
  }
  const int rowBase = by * 128;
  const int colBase = bx * 128;

  const unsigned short* Ap = A + (size_t)bz * (size_t)strideA + (size_t)rowBase * lda;
  const unsigned short* Bp = B + (size_t)bz * (size_t)strideB + (size_t)colBase * ldb;

  const int tid = threadIdx.x;
  const int wid = tid >> 6;
  const int lane = tid & 63;
  const int wr = wid >> 1;          // 0..1
  const int wc = wid & 1;           // 0..1
  const int fr = lane & 15;
  const int kgi = lane >> 4;        // 0..3
  const int rcol = ((kgi ^ ((fr >> 1) & 3)) * 8);  // swizzled read col (elems)

  const int nt = K >> 5;            // K-tiles of 32

  f32x4 acc[4][4] = {};

  // prologue: stage tile 0
  stage32(Ap, lda, &lds[0][0][0], tid);
  stage32(Bp, ldb, &lds[0][1][0], tid);
  __syncthreads();

  for (int t = 0; t < nt; ++t) {
    const int cur = t & 1;
    if (t + 1 < nt) {
      stage32(Ap + (size_t)(t + 1) * 32, lda, &lds[cur ^ 1][0][0], tid);
      stage32(Bp + (size_t)(t + 1) * 32, ldb, &lds[cur ^ 1][1][0], tid);
    }
    const unsigned short* sAc = &lds[cur][0][0];
    const unsigned short* sBc = &lds[cur][1][0];
    bf16x8 af[4], bv[4];
#pragma unroll
    for (int m = 0; m < 4; ++m)
      af[m] = *(const bf16x8*)&sAc[(wr * 64 + m * 16 + fr) * 32 + rcol];
#pragma unroll
    for (int n = 0; n < 4; ++n)
      bv[n] = *(const bf16x8*)&sBc[(wc * 64 + n * 16 + fr) * 32 + rcol];
#pragma unroll
    for (int m = 0; m < 4; ++m)
#pragma unroll
      for (int n = 0; n < 4; ++n)
        acc[m][n] = mfma16(af[m], bv[n], acc[m][n]);
    __syncthreads();   // drains vmcnt (next tile staged) + orders buffers
  }

  // ---- epilogue: C/D layout col=lane&15, row=(lane>>4)*4+j ----
  const int rg = (lane >> 4) * 4;
  const float* rsb = RSCALE ? rowsc + (size_t)bz * (size_t)rsStride : nullptr;

  if (OUT_BF16) {
    // pack bf16 C tile (128x128 = 32KB = whole LDS) then 16B coalesced stores
    unsigned short* cl = &lds[0][0][0];
#pragma unroll
    for (int m = 0; m < 4; ++m) {
      int rloc0 = wr * 64 + m * 16 + rg;
      float rs4[4];
      if (RSCALE) {
#pragma unroll
        for (int j = 0; j < 4; ++j) rs4[j] = rsb[rowBase + rloc0 + j];
      }
#pragma unroll
      for (int n = 0; n < 4; ++n) {
        int cloc = wc * 64 + n * 16 + fr;
        float bvs = 0.0f;
        if (HAS_BIAS) bvs = bias[colBase + cloc];
#pragma unroll
        for (int j = 0; j < 4; ++j) {
          int row = rloc0 + j;
          float v = acc[m][n][j] * alpha;
          if (EXPOUT) v = __expf(v);
          else v += bvs;
          if (RSCALE) v *= rs4[j];
          int gW = cloc >> 3;
          int gS = (gW & 8) | ((gW & 7) ^ (row & 7));
          cl[row * 128 + gS * 8 + (cloc & 7)] = f2bf(v);
        }
      }
    }
    __syncthreads();
    unsigned short* Cb =
        reinterpret_cast<unsigned short*>(Cv) + (size_t)bz * (size_t)strideC;
#pragma unroll
    for (int i = 0; i < 8; ++i) {
      int slot = i * 256 + tid;
      int row = slot >> 4, g = slot & 15;
      int gS = (g & 8) | ((g & 7) ^ (row & 7));
      bf16x8 v = *(const bf16x8*)&cl[row * 128 + gS * 8];
      *(bf16x8*)&Cb[(size_t)(rowBase + row) * ldc + colBase + g * 8] = v;
    }
  } else {
    // f32 path: two 64-row halves (each 64x128 f32 = 32KB = whole LDS)
    float* clf = reinterpret_cast<float*>(&lds[0][0][0]);
    float* Cf = reinterpret_cast<float*>(Cv) + (size_t)bz * (size_t)strideC;
#pragma unroll
    for (int half = 0; half < 2; ++half) {
      if (wr == half) {
#pragma unroll
        for (int m = 0; m < 4; ++m) {
          int rloc0 = m * 16 + rg;  // local row within half
          float rs4[4];
          if (RSCALE) {
#pragma unroll
            for (int j = 0; j < 4; ++j)
              rs4[j] = rsb[rowBase + half * 64 + rloc0 + j];
          }
#pragma unroll
          for (int n = 0; n < 4; ++n) {
            int cloc = wc * 64 + n * 16 + fr;
            float bvs = 0.0f;
            if (HAS_BIAS) bvs = bias[colBase + cloc];
#pragma unroll
            for (int j = 0; j < 4; ++j) {
              float v = acc[m][n][j] * alpha;
              if (EXPOUT) v = __expf(v);
              else v += bvs;
              if (RSCALE) v *= rs4[j];
              clf[(rloc0 + j) * 128 + cloc] = v;
            }
          }
        }
      }
      __syncthreads();
#pragma unroll
      for (int i = 0; i < 8; ++i) {
        int slot = i * 256 + tid;          // 64 rows x 32 float4-groups
        int row = slot >> 5, g = slot & 31;
        float4 v = *(const float4*)&clf[row * 128 + g * 4];
        *(float4*)&Cf[(size_t)(rowBase + half * 64 + row) * ldc + colBase + g * 4] = v;
      }
      __syncthreads();
    }
  }
}

// --------------------------- V transpose -----------------------------------
// Vt[b][d][s] = vbuf[(b*2048+s)*1024 + d]
__global__ void transpose_v(const unsigned short* __restrict__ vbuf,
                            unsigned short* __restrict__ vt) {
  __shared__ unsigned short tile[32][33];
  const int b = blockIdx.z;
  const int d0 = blockIdx.x * 32;
  const int s0 = blockIdx.y * 32;
  const int tx = threadIdx.x, ty = threadIdx.y;
#pragma unroll
  for (int i = 0; i < 32; i += 8)
    tile[ty + i][tx] =
        vbuf[(size_t)(b * 2048 + s0 + ty + i) * 1024 + d0 + tx];
  __syncthreads();
#pragma unroll
  for (int i = 0; i < 32; i += 8)
    vt[((size_t)b * 1024 + d0 + ty + i) * 2048 + s0 + tx] = tile[tx][ty + i];
}

// --------------------- row inverse-sum of P~ (bf16) ------------------------
__global__ __launch_bounds__(256) void rowsum_inv(
    const unsigned short* __restrict__ p, float* __restrict__ inv) {
  __shared__ float red[4];
  const size_t row = blockIdx.x;
  const unsigned short* pr = p + row * 2048;
  const int tid = threadIdx.x;

  ushort4 u0 = *reinterpret_cast<const ushort4*>(pr + tid * 8);
  ushort4 u1 = *reinterpret_cast<const ushort4*>(pr + tid * 8 + 4);
  float sum = bf2f(u0.x) + bf2f(u0.y) + bf2f(u0.z) + bf2f(u0.w) +
              bf2f(u1.x) + bf2f(u1.y) + bf2f(u1.z) + bf2f(u1.w);
#pragma unroll
  for (int off = 32; off; off >>= 1) sum += __shfl_xor(sum, off);
  if ((tid & 63) == 0) red[tid >> 6] = sum;
  __syncthreads();
  if (tid == 0) inv[row] = 1.0f / (red[0] + red[1] + red[2] + red[3]);
}

// ---------------------------------------------------------------------------
extern "C" void kernel_launch(void* const* d_in, const int* in_sizes, int n_in,
                              void* d_out, int out_size, void* d_ws, size_t ws_size,
                              hipStream_t stream) {
  const float* x     = (const float*)d_in[0];
  const float* Wqkv  = (const float*)d_in[1];
  const float* bqkv  = (const float*)d_in[2];
  const float* Wproj = (const float*)d_in[3];
  const float* bproj = (const float*)d_in[4];
  float* out = (float*)d_out;

  char* ws = (char*)d_ws;
  unsigned short* qk   = (unsigned short*)(ws + 0);          // 8192x2048 bf16
  unsigned short* vbuf = (unsigned short*)(ws + 33554432);   // 8192x1024 bf16
  unsigned short* xatt = (unsigned short*)(ws + 50331648);   // 8192x1024 bf16
  unsigned short* wq   = (unsigned short*)(ws + 67108864);   // 3072x1024 bf16
  float*          invs = (float*)(ws + 67108864);            // 8192 f32 (reuses wq late)
  unsigned short* wp   = (unsigned short*)(ws + 73400320);   // 1024x1024 bf16
  unsigned short* vt   = (unsigned short*)(ws + 75497472);   // 4x1024x2048 bf16
  unsigned short* sc   = (unsigned short*)(ws + 92274688);   // 4x2048x2048 bf16

  dim3 blk256(256);

  // 1. casts
  cvt_f32_bf16<<<2048, blk256, 0, stream>>>(x, xatt, 8192 * 1024);
  cvt_f32_bf16<<<1024, blk256, 0, stream>>>(Wqkv, wq, 3072 * 1024);
  cvt_f32_bf16<<<512, blk256, 0, stream>>>(Wproj, wp, 1024 * 1024);

  // 2a. QK projection: [8192,2048]  (grid 16x64 = 1024)
  gp<true, true, false, false><<<dim3(16, 64, 1), blk256, 0, stream>>>(
      xatt, wq, qk, bqkv, nullptr, 0,
      1024, 1024, 1024, 2048, 0, 0, 0, 1.0f);

  // 2b. V projection: [8192,1024]  (grid 8x64 = 512)
  gp<true, true, false, false><<<dim3(8, 64, 1), blk256, 0, stream>>>(
      xatt, wq + 2048 * 1024, vbuf, bqkv + 2048, nullptr, 0,
      1024, 1024, 1024, 1024, 0, 0, 0, 1.0f);

  // 3. V transpose -> Vt[b][d][s]
  transpose_v<<<dim3(32, 64, 4), dim3(32, 8), 0, stream>>>(vbuf, vt);

  // 4. P~ = exp(Q @ K^T / 32)  (grid 16x16x4 = 1024)
  gp<true, false, true, false><<<dim3(16, 16, 4), blk256, 0, stream>>>(
      qk, qk + 1024, sc, nullptr, nullptr, 0,
      1024, 2048, 2048, 2048,
      2048LL * 2048, 2048LL * 2048, 2048LL * 2048, 0.03125f);

  // 5. inv[row] = 1/rowsum(P~)
  rowsum_inv<<<8192, blk256, 0, stream>>>(sc, invs);

  // 6. attn_out = (P~ @ Vt) * inv[row]  (grid 8x16x4 = 512)
  gp<true, false, false, true><<<dim3(8, 16, 4), blk256, 0, stream>>>(
      sc, vt, xatt, nullptr, invs, 2048,
      2048, 2048, 2048, 1024,
      2048LL * 2048, 1024LL * 2048, 2048LL * 1024, 1.0f);

  // 7. out = attn_out @ Wproj^T + b_proj  (grid 8x64 = 512)
  gp<false, true, false, false><<<dim3(8, 64, 1), blk256, 0, stream>>>(
      xatt, wp, out, bproj, nullptr, 0,
      1024, 1024, 1024, 1024, 0, 0, 0, 1.0f);
}

// Round 10
// 176.916 us; speedup vs baseline: 1.2277x; 1.2277x over previous
//
#include <hip/hip_runtime.h>
#include <stdint.h>
#include <stddef.h>

// ---------------------------------------------------------------------------
// AttentionLayer: x[4,2048,1024] f32, W_qkv[3072,1024], b_qkv[3072],
//                 W_proj[1024,1024], b_proj[1024]  -> out[4,2048,1024] f32
// Uniform GEMM "gf": 128x128 tile, BK=64, 4 waves, 1 barrier/K-tile, 64KB LDS
// dbuf -> 2 blocks/CU, 8x8 L2 block-tiling. Fusions: V-proj writes V^T
// directly (transposed LDS epilogue); QK^T writes exp(s/32) AND per-block row
// partial sums (shfl in store pass); inv_from_partial makes 1/rowsum; PV
// scales by it. No separate transpose or rowsum passes.
// ---------------------------------------------------------------------------

typedef __attribute__((ext_vector_type(8))) short bf16x8;
typedef __attribute__((ext_vector_type(4))) float f32x4;

__device__ __forceinline__ unsigned short f2bf(float f) {
  unsigned u = __float_as_uint(f);
  u += 0x7fffu + ((u >> 16) & 1u);
  return (unsigned short)(u >> 16);
}
__device__ __forceinline__ float bf2f(unsigned short h) {
  return __uint_as_float(((unsigned)h) << 16);
}

typedef const __attribute__((address_space(1))) void* gas_ptr;
typedef __attribute__((address_space(3))) void* las_ptr;

__device__ __forceinline__ void gload_lds16(const void* g, void* l) {
  __builtin_amdgcn_global_load_lds((gas_ptr)(uintptr_t)g,
                                   (las_ptr)(uint32_t)(uintptr_t)l, 16, 0, 0);
}

__device__ __forceinline__ f32x4 mfma16(bf16x8 a, bf16x8 b, f32x4 c) {
  return __builtin_amdgcn_mfma_f32_16x16x32_bf16(a, b, c, 0, 0, 0);
}

// --------------------------- fp32 -> bf16 cast -----------------------------
__global__ __launch_bounds__(256) void cvt_f32_bf16(
    const float* __restrict__ in, unsigned short* __restrict__ out, int n) {
  int i = (blockIdx.x * blockDim.x + threadIdx.x) * 4;
  int stride = gridDim.x * blockDim.x * 4;
  for (; i < n; i += stride) {
    float4 v = *reinterpret_cast<const float4*>(in + i);
    ushort4 o;
    o.x = f2bf(v.x); o.y = f2bf(v.y); o.z = f2bf(v.z); o.w = f2bf(v.w);
    *reinterpret_cast<ushort4*>(out + i) = o;
  }
}

// ================================ gf =======================================
__device__ __forceinline__ void stage_gf(const unsigned short* __restrict__ P,
                                         int ld, unsigned short* dst, int wid,
                                         int lane) {
#pragma unroll
  for (int c = 0; c < 4; ++c) {
    int s = (c * 4 + wid) * 64 + lane;
    int row = s >> 3, g = s & 7;
    gload_lds16(P + (size_t)row * ld + ((g ^ (row & 7)) * 8),
                dst + (c * 4 + wid) * 512);
  }
}

// TRANSOUT: write C transposed as Vt[(b*1024+colBase+d)*2048 + s] (V-proj).
// RSUM: also write per-row partial sums rsum[(bz*2048+row)*16 + bx] (QK^T).
template <bool OUT_BF16, bool HAS_BIAS, bool EXPOUT, bool RSCALE,
          bool TRANSOUT, bool RSUM>
__global__ __launch_bounds__(256, 2) void gf(
    const unsigned short* __restrict__ A, const unsigned short* __restrict__ B,
    void* __restrict__ Cv, const float* __restrict__ bias,
    const float* __restrict__ rowsc, float* __restrict__ rsum, int rsStride,
    int K, int lda, int ldb, int ldc,
    long long strideA, long long strideB, long long strideC, float alpha) {
  __shared__ unsigned short lds[2][2][128 * 64];  // 64KB

  const int bz = blockIdx.z;
  const int gx = gridDim.x;
  int lin = blockIdx.y * gx + blockIdx.x;
  int bx, by;
  {
    const int nwg = gx * gridDim.y;
    const int q = nwg >> 3;                 // XCD chunking (nwg % 8 == 0)
    lin = (lin & 7) * q + (lin >> 3);
    const int t = lin >> 6, r = lin & 63;   // 8x8 tile ordering per 64 blocks
    const int tilesX = gx >> 3;
    bx = (t % tilesX) * 8 + (r & 7);
    by = (t / tilesX) * 8 + (r >> 3);
  }
  const int rowBase = by * 128;
  const int colBase = bx * 128;

  const unsigned short* Ap = A + (size_t)bz * (size_t)strideA + (size_t)rowBase * lda;
  const unsigned short* Bp = B + (size_t)bz * (size_t)strideB + (size_t)colBase * ldb;

  const int tid = threadIdx.x;
  const int wid = tid >> 6;
  const int lane = tid & 63;
  const int wr = wid >> 1;
  const int wc = wid & 1;
  const int fr = lane & 15;
  const int kgi = lane >> 4;

  const int nt = K >> 6;

  f32x4 acc[4][4] = {};

  stage_gf(Ap, lda, &lds[0][0][0], wid, lane);
  stage_gf(Bp, ldb, &lds[0][1][0], wid, lane);
  asm volatile("s_waitcnt vmcnt(0)" ::: "memory");
  __builtin_amdgcn_sched_barrier(0);
  __builtin_amdgcn_s_barrier();

  for (int t = 0; t < nt; ++t) {
    const int cur = t & 1;
    if (t + 1 < nt) {
      stage_gf(Ap + (size_t)(t + 1) * 64, lda, &lds[cur ^ 1][0][0], wid, lane);
      stage_gf(Bp + (size_t)(t + 1) * 64, ldb, &lds[cur ^ 1][1][0], wid, lane);
    }
    const unsigned short* sAc = &lds[cur][0][0];
    const unsigned short* sBc = &lds[cur][1][0];

    bf16x8 af[4][2], bv[4][2];
#pragma unroll
    for (int m = 0; m < 4; ++m) {
      int row = wr * 64 + m * 16 + fr;
      int r7 = row & 7;
      af[m][0] = *(const bf16x8*)&sAc[row * 64 + ((kgi ^ r7) * 8)];
      af[m][1] = *(const bf16x8*)&sAc[row * 64 + (((4 + kgi) ^ r7) * 8)];
    }
#pragma unroll
    for (int n = 0; n < 4; ++n) {
      int row = wc * 64 + n * 16 + fr;
      int r7 = row & 7;
      bv[n][0] = *(const bf16x8*)&sBc[row * 64 + ((kgi ^ r7) * 8)];
      bv[n][1] = *(const bf16x8*)&sBc[row * 64 + (((4 + kgi) ^ r7) * 8)];
    }
    asm volatile("s_waitcnt lgkmcnt(0)" ::: "memory");
    __builtin_amdgcn_sched_barrier(0);
    __builtin_amdgcn_s_setprio(1);
#pragma unroll
    for (int m = 0; m < 4; ++m)
#pragma unroll
      for (int n = 0; n < 4; ++n) {
        acc[m][n] = mfma16(af[m][0], bv[n][0], acc[m][n]);
        acc[m][n] = mfma16(af[m][1], bv[n][1], acc[m][n]);
      }
    __builtin_amdgcn_s_setprio(0);
    __builtin_amdgcn_sched_barrier(0);
    asm volatile("s_waitcnt vmcnt(0)" ::: "memory");
    __builtin_amdgcn_sched_barrier(0);
    __builtin_amdgcn_s_barrier();
  }

  // ---- epilogue: C/D layout col=lane&15, row=(lane>>4)*4+j ----
  const int rg = (lane >> 4) * 4;
  const float* rsb = RSCALE ? rowsc + (size_t)bz * (size_t)rsStride : nullptr;

  if (TRANSOUT) {
    // transposed pack: cl[d][s], d = local col (0..127), s = local row,
    // padded row length 136 shorts (16B-aligned rows, conflict-benign).
    unsigned short* cl = &lds[0][0][0];  // 128*136*2 = 34816 B
#pragma unroll
    for (int m = 0; m < 4; ++m) {
      int rloc0 = wr * 64 + m * 16 + rg;
#pragma unroll
      for (int n = 0; n < 4; ++n) {
        int cloc = wc * 64 + n * 16 + fr;
        float bvs = HAS_BIAS ? bias[colBase + cloc] : 0.0f;
#pragma unroll
        for (int j = 0; j < 4; ++j) {
          float v = acc[m][n][j] * alpha + bvs;
          cl[cloc * 136 + rloc0 + j] = f2bf(v);
        }
      }
    }
    __syncthreads();
    // store: Vt[(b*1024 + colBase + d)*2048 + s0 + sg*8]
    const int b = rowBase >> 11;
    const int s0 = rowBase & 2047;
    unsigned short* Vt = reinterpret_cast<unsigned short*>(Cv);
#pragma unroll
    for (int i = 0; i < 8; ++i) {
      int slot = i * 256 + tid;           // 128 d x 16 s-groups
      int d = slot >> 4, sg = slot & 15;
      bf16x8 v = *(const bf16x8*)&cl[d * 136 + sg * 8];
      *(bf16x8*)&Vt[((size_t)(b * 1024 + colBase + d)) * 2048 + s0 + sg * 8] = v;
    }
  } else if (OUT_BF16) {
    unsigned short* cl = &lds[0][0][0];  // 32KB bf16 tile
#pragma unroll
    for (int m = 0; m < 4; ++m) {
      int rloc0 = wr * 64 + m * 16 + rg;
      float rs4[4];
      if (RSCALE) {
#pragma unroll
        for (int j = 0; j < 4; ++j) rs4[j] = rsb[rowBase + rloc0 + j];
      }
#pragma unroll
      for (int n = 0; n < 4; ++n) {
        int cloc = wc * 64 + n * 16 + fr;
        float bvs = 0.0f;
        if (HAS_BIAS) bvs = bias[colBase + cloc];
#pragma unroll
        for (int j = 0; j < 4; ++j) {
          int row = rloc0 + j;
          float v = acc[m][n][j] * alpha;
          if (EXPOUT) v = __expf(v);
          else v += bvs;
          if (RSCALE) v *= rs4[j];
          int gW = cloc >> 3;
          int gS = (gW & 8) | ((gW & 7) ^ (row & 7));
          cl[row * 128 + gS * 8 + (cloc & 7)] = f2bf(v);
        }
      }
    }
    __syncthreads();
    unsigned short* Cb =
        reinterpret_cast<unsigned short*>(Cv) + (size_t)bz * (size_t)strideC;
#pragma unroll
    for (int i = 0; i < 8; ++i) {
      int slot = i * 256 + tid;
      int row = slot >> 4, g = slot & 15;
      int gS = (g & 8) | ((g & 7) ^ (row & 7));
      bf16x8 v = *(const bf16x8*)&cl[row * 128 + gS * 8];
      *(bf16x8*)&Cb[(size_t)(rowBase + row) * ldc + colBase + g * 8] = v;
      if (RSUM) {
        // per-row partial sum over this block's 128 cols: 16 lanes (g) hold
        // 8 cols each for the same row -> shfl-reduce within the 16-group.
        float s8 = 0.0f;
#pragma unroll
        for (int k = 0; k < 8; ++k) s8 += bf2f((unsigned short)v[k]);
        s8 += __shfl_xor(s8, 1);
        s8 += __shfl_xor(s8, 2);
        s8 += __shfl_xor(s8, 4);
        s8 += __shfl_xor(s8, 8);
        if ((lane & 15) == 0)
          rsum[((size_t)bz * 2048 + rowBase + row) * 16 + bx] = s8;
      }
    }
  } else {
    // f32 path via LDS: coalesced float4 stores
    float* clf = reinterpret_cast<float*>(&lds[0][0][0]);
#pragma unroll
    for (int m = 0; m < 4; ++m) {
      int rloc0 = wr * 64 + m * 16 + rg;
      float rs4[4];
      if (RSCALE) {
#pragma unroll
        for (int j = 0; j < 4; ++j) rs4[j] = rsb[rowBase + rloc0 + j];
      }
#pragma unroll
      for (int n = 0; n < 4; ++n) {
        int cloc = wc * 64 + n * 16 + fr;
        float bvs = 0.0f;
        if (HAS_BIAS) bvs = bias[colBase + cloc];
#pragma unroll
        for (int j = 0; j < 4; ++j) {
          int row = rloc0 + j;
          float v = acc[m][n][j] * alpha;
          if (EXPOUT) v = __expf(v);
          else v += bvs;
          if (RSCALE) v *= rs4[j];
          int gW = cloc >> 2;
          int gS = (gW & 24) | ((gW & 7) ^ (row & 7));
          clf[row * 128 + gS * 4 + (cloc & 3)] = v;
        }
      }
    }
    __syncthreads();
    float* Cf = reinterpret_cast<float*>(Cv) + (size_t)bz * (size_t)strideC;
#pragma unroll
    for (int i = 0; i < 16; ++i) {
      int slot = i * 256 + tid;
      int row = slot >> 5, g = slot & 31;
      int gS = (g & 24) | ((g & 7) ^ (row & 7));
      float4 v = *(const float4*)&clf[row * 128 + gS * 4];
      *(float4*)&Cf[(size_t)(rowBase + row) * ldc + colBase + g * 4] = v;
    }
  }
}

// ---------------- inv[row] = 1 / sum_16 partial[row][*] --------------------
__global__ __launch_bounds__(256) void inv_from_partial(
    const float* __restrict__ rs, float* __restrict__ inv) {
  int r = blockIdx.x * 256 + threadIdx.x;  // 8192 rows
  const float4* p = reinterpret_cast<const float4*>(rs + (size_t)r * 16);
  float4 a = p[0], b = p[1], c = p[2], d = p[3];
  float s = a.x + a.y + a.z + a.w + b.x + b.y + b.z + b.w +
            c.x + c.y + c.z + c.w + d.x + d.y + d.z + d.w;
  inv[r] = 1.0f / s;
}

// ---------------------------------------------------------------------------
extern "C" void kernel_launch(void* const* d_in, const int* in_sizes, int n_in,
                              void* d_out, int out_size, void* d_ws, size_t ws_size,
                              hipStream_t stream) {
  const float* x     = (const float*)d_in[0];
  const float* Wqkv  = (const float*)d_in[1];
  const float* bqkv  = (const float*)d_in[2];
  const float* Wproj = (const float*)d_in[3];
  const float* bproj = (const float*)d_in[4];
  float* out = (float*)d_out;

  char* ws = (char*)d_ws;
  unsigned short* qk   = (unsigned short*)(ws + 0);          // 8192x2048 bf16
  unsigned short* xatt = (unsigned short*)(ws + 50331648);   // 8192x1024 bf16
  unsigned short* wq   = (unsigned short*)(ws + 67108864);   // 3072x1024 bf16 (early)
  float*          invs = (float*)(ws + 33554432);            // 8192 f32 (dead vbuf slot)
  float*          rsp  = (float*)(ws + 33554432 + 65536);    // 8192x16 f32 partials
  unsigned short* wp   = (unsigned short*)(ws + 73400320);   // 1024x1024 bf16
  unsigned short* vt   = (unsigned short*)(ws + 75497472);   // 4x1024x2048 bf16
  unsigned short* sc   = (unsigned short*)(ws + 92274688);   // 4x2048x2048 bf16

  dim3 blk256(256);

  // 1. casts
  cvt_f32_bf16<<<2048, blk256, 0, stream>>>(x, xatt, 8192 * 1024);
  cvt_f32_bf16<<<1024, blk256, 0, stream>>>(Wqkv, wq, 3072 * 1024);
  cvt_f32_bf16<<<512, blk256, 0, stream>>>(Wproj, wp, 1024 * 1024);

  // 2a. QK projection: [8192,2048]  (grid 16x64 = 1024)
  gf<true, true, false, false, false, false><<<dim3(16, 64, 1), blk256, 0, stream>>>(
      xatt, wq, qk, bqkv, nullptr, nullptr, 0,
      1024, 1024, 1024, 2048, 0, 0, 0, 1.0f);

  // 2b. V projection -> writes V^T directly  (grid 8x64 = 512)
  gf<true, true, false, false, true, false><<<dim3(8, 64, 1), blk256, 0, stream>>>(
      xatt, wq + 2048 * 1024, vt, bqkv + 2048, nullptr, nullptr, 0,
      1024, 1024, 1024, 2048, 0, 0, 0, 1.0f);

  // 3. P~ = exp(Q @ K^T / 32) + row partial sums  (grid 16x16x4 = 1024)
  gf<true, false, true, false, false, true><<<dim3(16, 16, 4), blk256, 0, stream>>>(
      qk, qk + 1024, sc, nullptr, nullptr, rsp, 0,
      1024, 2048, 2048, 2048,
      2048LL * 2048, 2048LL * 2048, 2048LL * 2048, 0.03125f);

  // 4. inv[row] = 1/rowsum  (32 blocks)
  inv_from_partial<<<32, blk256, 0, stream>>>(rsp, invs);

  // 5. attn_out = (P~ @ Vt) * inv[row]  (grid 8x16x4 = 512)
  gf<true, false, false, true, false, false><<<dim3(8, 16, 4), blk256, 0, stream>>>(
      sc, vt, xatt, nullptr, invs, nullptr, 2048,
      2048, 2048, 2048, 1024,
      2048LL * 2048, 1024LL * 2048, 2048LL * 1024, 1.0f);

  // 6. out = attn_out @ Wproj^T + b_proj  (grid 8x64 = 512)
  gf<false, true, false, false, false, false><<<dim3(8, 64, 1), blk256, 0, stream>>>(
      xatt, wp, out, bproj, nullptr, nullptr, 0,
      1024, 1024, 1024, 1024, 0, 0, 0, 1.0f);
}

// Round 11
// 176.581 us; speedup vs baseline: 1.2300x; 1.0019x over previous
//
#include <hip/hip_runtime.h>
#include <stdint.h>
#include <stddef.h>

// ---------------------------------------------------------------------------
// AttentionLayer: x[4,2048,1024] f32, W_qkv[3072,1024], b_qkv[3072],
//                 W_proj[1024,1024], b_proj[1024]  -> out[4,2048,1024] f32
// Uniform GEMM "gf": 128x128 tile, BK=64, 4 waves, 1 barrier/K-tile, 64KB LDS
// dbuf -> 2 blocks/CU, 8x8 L2 block-tiling. Fusions: V-proj writes V^T
// directly; QK^T writes exp(s/32); PV computes rowsums IN-KERNEL via a
// ones-vector MFMA on its A (P~) fragments and divides in its epilogue.
// No separate transpose / rowsum / inv kernels.
// ---------------------------------------------------------------------------

typedef __attribute__((ext_vector_type(8))) short bf16x8;
typedef __attribute__((ext_vector_type(4))) float f32x4;

__device__ __forceinline__ unsigned short f2bf(float f) {
  unsigned u = __float_as_uint(f);
  u += 0x7fffu + ((u >> 16) & 1u);
  return (unsigned short)(u >> 16);
}
__device__ __forceinline__ float bf2f(unsigned short h) {
  return __uint_as_float(((unsigned)h) << 16);
}

typedef const __attribute__((address_space(1))) void* gas_ptr;
typedef __attribute__((address_space(3))) void* las_ptr;

__device__ __forceinline__ void gload_lds16(const void* g, void* l) {
  __builtin_amdgcn_global_load_lds((gas_ptr)(uintptr_t)g,
                                   (las_ptr)(uint32_t)(uintptr_t)l, 16, 0, 0);
}

__device__ __forceinline__ f32x4 mfma16(bf16x8 a, bf16x8 b, f32x4 c) {
  return __builtin_amdgcn_mfma_f32_16x16x32_bf16(a, b, c, 0, 0, 0);
}

// --------------------------- fp32 -> bf16 cast -----------------------------
__global__ __launch_bounds__(256) void cvt_f32_bf16(
    const float* __restrict__ in, unsigned short* __restrict__ out, int n) {
  int i = (blockIdx.x * blockDim.x + threadIdx.x) * 4;
  int stride = gridDim.x * blockDim.x * 4;
  for (; i < n; i += stride) {
    float4 v = *reinterpret_cast<const float4*>(in + i);
    ushort4 o;
    o.x = f2bf(v.x); o.y = f2bf(v.y); o.z = f2bf(v.z); o.w = f2bf(v.w);
    *reinterpret_cast<ushort4*>(out + i) = o;
  }
}

// ================================ gf =======================================
__device__ __forceinline__ void stage_gf(const unsigned short* __restrict__ P,
                                         int ld, unsigned short* dst, int wid,
                                         int lane) {
#pragma unroll
  for (int c = 0; c < 4; ++c) {
    int s = (c * 4 + wid) * 64 + lane;
    int row = s >> 3, g = s & 7;
    gload_lds16(P + (size_t)row * ld + ((g ^ (row & 7)) * 8),
                dst + (c * 4 + wid) * 512);
  }
}

// TRANSOUT: write C transposed as Vt[(b*1024+colBase+d)*2048 + s] (V-proj).
// RINV: accumulate rowsum(A) via ones-MFMA; epilogue multiplies by 1/rowsum.
template <bool OUT_BF16, bool HAS_BIAS, bool EXPOUT, bool TRANSOUT, bool RINV>
__global__ __launch_bounds__(256, 2) void gf(
    const unsigned short* __restrict__ A, const unsigned short* __restrict__ B,
    void* __restrict__ Cv, const float* __restrict__ bias,
    int K, int lda, int ldb, int ldc,
    long long strideA, long long strideB, long long strideC, float alpha) {
  __shared__ unsigned short lds[2][2][128 * 64];  // 64KB

  const int bz = blockIdx.z;
  const int gx = gridDim.x;
  int lin = blockIdx.y * gx + blockIdx.x;
  int bx, by;
  {
    const int nwg = gx * gridDim.y;
    const int q = nwg >> 3;                 // XCD chunking (nwg % 8 == 0)
    lin = (lin & 7) * q + (lin >> 3);
    const int t = lin >> 6, r = lin & 63;   // 8x8 tile ordering per 64 blocks
    const int tilesX = gx >> 3;
    bx = (t % tilesX) * 8 + (r & 7);
    by = (t / tilesX) * 8 + (r >> 3);
  }
  const int rowBase = by * 128;
  const int colBase = bx * 128;

  const unsigned short* Ap = A + (size_t)bz * (size_t)strideA + (size_t)rowBase * lda;
  const unsigned short* Bp = B + (size_t)bz * (size_t)strideB + (size_t)colBase * ldb;

  const int tid = threadIdx.x;
  const int wid = tid >> 6;
  const int lane = tid & 63;
  const int wr = wid >> 1;
  const int wc = wid & 1;
  const int fr = lane & 15;
  const int kgi = lane >> 4;

  const int nt = K >> 6;

  f32x4 acc[4][4] = {};
  f32x4 rsacc[4] = {};
  bf16x8 ones;
#pragma unroll
  for (int i = 0; i < 8; ++i) ones[i] = (short)0x3F80;  // bf16 1.0

  stage_gf(Ap, lda, &lds[0][0][0], wid, lane);
  stage_gf(Bp, ldb, &lds[0][1][0], wid, lane);
  asm volatile("s_waitcnt vmcnt(0)" ::: "memory");
  __builtin_amdgcn_sched_barrier(0);
  __builtin_amdgcn_s_barrier();

  for (int t = 0; t < nt; ++t) {
    const int cur = t & 1;
    if (t + 1 < nt) {
      stage_gf(Ap + (size_t)(t + 1) * 64, lda, &lds[cur ^ 1][0][0], wid, lane);
      stage_gf(Bp + (size_t)(t + 1) * 64, ldb, &lds[cur ^ 1][1][0], wid, lane);
    }
    const unsigned short* sAc = &lds[cur][0][0];
    const unsigned short* sBc = &lds[cur][1][0];

    bf16x8 af[4][2], bv[4][2];
#pragma unroll
    for (int m = 0; m < 4; ++m) {
      int row = wr * 64 + m * 16 + fr;
      int r7 = row & 7;
      af[m][0] = *(const bf16x8*)&sAc[row * 64 + ((kgi ^ r7) * 8)];
      af[m][1] = *(const bf16x8*)&sAc[row * 64 + (((4 + kgi) ^ r7) * 8)];
    }
#pragma unroll
    for (int n = 0; n < 4; ++n) {
      int row = wc * 64 + n * 16 + fr;
      int r7 = row & 7;
      bv[n][0] = *(const bf16x8*)&sBc[row * 64 + ((kgi ^ r7) * 8)];
      bv[n][1] = *(const bf16x8*)&sBc[row * 64 + (((4 + kgi) ^ r7) * 8)];
    }
    asm volatile("s_waitcnt lgkmcnt(0)" ::: "memory");
    __builtin_amdgcn_sched_barrier(0);
    __builtin_amdgcn_s_setprio(1);
#pragma unroll
    for (int m = 0; m < 4; ++m)
#pragma unroll
      for (int n = 0; n < 4; ++n) {
        acc[m][n] = mfma16(af[m][0], bv[n][0], acc[m][n]);
        acc[m][n] = mfma16(af[m][1], bv[n][1], acc[m][n]);
      }
    if (RINV) {
#pragma unroll
      for (int m = 0; m < 4; ++m) {
        rsacc[m] = mfma16(af[m][0], ones, rsacc[m]);
        rsacc[m] = mfma16(af[m][1], ones, rsacc[m]);
      }
    }
    __builtin_amdgcn_s_setprio(0);
    __builtin_amdgcn_sched_barrier(0);
    asm volatile("s_waitcnt vmcnt(0)" ::: "memory");
    __builtin_amdgcn_sched_barrier(0);
    __builtin_amdgcn_s_barrier();
  }

  // ---- epilogue: C/D layout col=lane&15, row=(lane>>4)*4+j ----
  const int rg = (lane >> 4) * 4;

  if (TRANSOUT) {
    // transposed pack: cl[d][s], padded row 136 shorts
    unsigned short* cl = &lds[0][0][0];
#pragma unroll
    for (int m = 0; m < 4; ++m) {
      int rloc0 = wr * 64 + m * 16 + rg;
#pragma unroll
      for (int n = 0; n < 4; ++n) {
        int cloc = wc * 64 + n * 16 + fr;
        float bvs = HAS_BIAS ? bias[colBase + cloc] : 0.0f;
#pragma unroll
        for (int j = 0; j < 4; ++j) {
          float v = acc[m][n][j] * alpha + bvs;
          cl[cloc * 136 + rloc0 + j] = f2bf(v);
        }
      }
    }
    __syncthreads();
    const int b = rowBase >> 11;
    const int s0 = rowBase & 2047;
    unsigned short* Vt = reinterpret_cast<unsigned short*>(Cv);
#pragma unroll
    for (int i = 0; i < 8; ++i) {
      int slot = i * 256 + tid;
      int d = slot >> 4, sg = slot & 15;
      bf16x8 v = *(const bf16x8*)&cl[d * 136 + sg * 8];
      *(bf16x8*)&Vt[((size_t)(b * 1024 + colBase + d)) * 2048 + s0 + sg * 8] = v;
    }
  } else if (OUT_BF16) {
    unsigned short* cl = &lds[0][0][0];
#pragma unroll
    for (int m = 0; m < 4; ++m) {
      int rloc0 = wr * 64 + m * 16 + rg;
      float rs4[4];
      if (RINV) {
#pragma unroll
        for (int j = 0; j < 4; ++j) rs4[j] = 1.0f / rsacc[m][j];
      }
#pragma unroll
      for (int n = 0; n < 4; ++n) {
        int cloc = wc * 64 + n * 16 + fr;
        float bvs = 0.0f;
        if (HAS_BIAS) bvs = bias[colBase + cloc];
#pragma unroll
        for (int j = 0; j < 4; ++j) {
          int row = rloc0 + j;
          float v = acc[m][n][j] * alpha;
          if (EXPOUT) v = __expf(v);
          else v += bvs;
          if (RINV) v *= rs4[j];
          int gW = cloc >> 3;
          int gS = (gW & 8) | ((gW & 7) ^ (row & 7));
          cl[row * 128 + gS * 8 + (cloc & 7)] = f2bf(v);
        }
      }
    }
    __syncthreads();
    unsigned short* Cb =
        reinterpret_cast<unsigned short*>(Cv) + (size_t)bz * (size_t)strideC;
#pragma unroll
    for (int i = 0; i < 8; ++i) {
      int slot = i * 256 + tid;
      int row = slot >> 4, g = slot & 15;
      int gS = (g & 8) | ((g & 7) ^ (row & 7));
      bf16x8 v = *(const bf16x8*)&cl[row * 128 + gS * 8];
      *(bf16x8*)&Cb[(size_t)(rowBase + row) * ldc + colBase + g * 8] = v;
    }
  } else {
    // f32 path via LDS: coalesced float4 stores
    float* clf = reinterpret_cast<float*>(&lds[0][0][0]);
#pragma unroll
    for (int m = 0; m < 4; ++m) {
      int rloc0 = wr * 64 + m * 16 + rg;
#pragma unroll
      for (int n = 0; n < 4; ++n) {
        int cloc = wc * 64 + n * 16 + fr;
        float bvs = 0.0f;
        if (HAS_BIAS) bvs = bias[colBase + cloc];
#pragma unroll
        for (int j = 0; j < 4; ++j) {
          int row = rloc0 + j;
          float v = acc[m][n][j] * alpha + bvs;
          int gW = cloc >> 2;
          int gS = (gW & 24) | ((gW & 7) ^ (row & 7));
          clf[row * 128 + gS * 4 + (cloc & 3)] = v;
        }
      }
    }
    __syncthreads();
    float* Cf = reinterpret_cast<float*>(Cv) + (size_t)bz * (size_t)strideC;
#pragma unroll
    for (int i = 0; i < 16; ++i) {
      int slot = i * 256 + tid;
      int row = slot >> 5, g = slot & 31;
      int gS = (g & 24) | ((g & 7) ^ (row & 7));
      float4 v = *(const float4*)&clf[row * 128 + gS * 4];
      *(float4*)&Cf[(size_t)(rowBase + row) * ldc + colBase + g * 4] = v;
    }
  }
}

// ---------------------------------------------------------------------------
extern "C" void kernel_launch(void* const* d_in, const int* in_sizes, int n_in,
                              void* d_out, int out_size, void* d_ws, size_t ws_size,
                              hipStream_t stream) {
  const float* x     = (const float*)d_in[0];
  const float* Wqkv  = (const float*)d_in[1];
  const float* bqkv  = (const float*)d_in[2];
  const float* Wproj = (const float*)d_in[3];
  const float* bproj = (const float*)d_in[4];
  float* out = (float*)d_out;

  char* ws = (char*)d_ws;
  unsigned short* qk   = (unsigned short*)(ws + 0);          // 8192x2048 bf16
  unsigned short* xatt = (unsigned short*)(ws + 50331648);   // 8192x1024 bf16
  unsigned short* wq   = (unsigned short*)(ws + 67108864);   // 3072x1024 bf16
  unsigned short* wp   = (unsigned short*)(ws + 73400320);   // 1024x1024 bf16
  unsigned short* vt   = (unsigned short*)(ws + 75497472);   // 4x1024x2048 bf16
  unsigned short* sc   = (unsigned short*)(ws + 92274688);   // 4x2048x2048 bf16

  dim3 blk256(256);

  // 1. casts
  cvt_f32_bf16<<<2048, blk256, 0, stream>>>(x, xatt, 8192 * 1024);
  cvt_f32_bf16<<<1024, blk256, 0, stream>>>(Wqkv, wq, 3072 * 1024);
  cvt_f32_bf16<<<512, blk256, 0, stream>>>(Wproj, wp, 1024 * 1024);

  // 2a. QK projection: [8192,2048]  (grid 16x64 = 1024)
  gf<true, true, false, false, false><<<dim3(16, 64, 1), blk256, 0, stream>>>(
      xatt, wq, qk, bqkv,
      1024, 1024, 1024, 2048, 0, 0, 0, 1.0f);

  // 2b. V projection -> writes V^T directly  (grid 8x64 = 512)
  gf<true, true, false, true, false><<<dim3(8, 64, 1), blk256, 0, stream>>>(
      xatt, wq + 2048 * 1024, vt, bqkv + 2048,
      1024, 1024, 1024, 2048, 0, 0, 0, 1.0f);

  // 3. P~ = exp(Q @ K^T / 32)  (grid 16x16x4 = 1024)
  gf<true, false, true, false, false><<<dim3(16, 16, 4), blk256, 0, stream>>>(
      qk, qk + 1024, sc, nullptr,
      1024, 2048, 2048, 2048,
      2048LL * 2048, 2048LL * 2048, 2048LL * 2048, 0.03125f);

  // 4. attn_out = (P~ @ Vt) / rowsum(P~)  (grid 8x16x4 = 512; rowsum via
  //    ones-MFMA on the P~ fragments already in registers)
  gf<true, false, false, false, true><<<dim3(8, 16, 4), blk256, 0, stream>>>(
      sc, vt, xatt, nullptr,
      2048, 2048, 2048, 1024,
      2048LL * 2048, 1024LL * 2048, 2048LL * 1024, 1.0f);

  // 5. out = attn_out @ Wproj^T + b_proj  (grid 8x64 = 512)
  gf<false, true, false, false, false><<<dim3(8, 64, 1), blk256, 0, stream>>>(
      xatt, wp, out, bproj,
      1024, 1024, 1024, 1024, 0, 0, 0, 1.0f);
}